// Round 4
// baseline (111.985 us; speedup 1.0000x reference)
//
#include <hip/hip_runtime.h>

// SPQR dequant-GEMV: y[b][m] = sum_n x[b][n] * Wd[m][n] + CSR outlier correction
// M=N=8192, beta1=beta2=16, B(=b*l)=10, 32 nnz/row.
// R4: cross-chunk double-buffered register prefetch (named A/B bufs, unroll-2),
//     2 cols/thread so both buffers fit; 3 waves/SIMD. Theory: keep next
//     chunk's HBM loads in flight during current chunk's compute phase.

constexpr int M_DIM = 8192;
constexpr int N_DIM = 8192;
constexpr int TN    = 512;          // N / 16
constexpr int BQ    = 10;           // batch (b*l)
constexpr int RB    = 4;            // rows per block
constexpr int NTHREADS = 256;
constexpr int CC    = NTHREADS * 2; // 512 columns per chunk (2 cols/thread)
constexpr int NCHUNK = N_DIM / CC;  // 16
constexpr int NOUT  = RB * BQ;      // 40 partial outputs per block

typedef float v2f __attribute__((ext_vector_type(2)));
typedef int   v2i __attribute__((ext_vector_type(2)));

struct Buf {
    v2f   xv[BQ];                   // 20 VGPR
    v2i   wc[RB];                   // 8
    int   sraw[RB];                 // 4
    int   zraw[RB];                 // 4
    float wss, wsz, wzs, wzz;       // 4
};

__global__ __launch_bounds__(NTHREADS, 3)
void spqr_fused(const float* __restrict__ x,
                const int*   __restrict__ W,
                const int*   __restrict__ Ws,
                const int*   __restrict__ Wz,
                const float* __restrict__ Wss,
                const float* __restrict__ Wsz,
                const float* __restrict__ Wzs,
                const float* __restrict__ Wzz,
                const int*   __restrict__ row_offsets,
                const int*   __restrict__ col_ids,
                const float* __restrict__ values,
                float*       __restrict__ y)
{
    const int t  = threadIdx.x;
    const int m0 = blockIdx.x * RB;
    const int ti = m0 >> 4;                 // all 4 rows in the same 16-row tile
    const int tc = t * 2;

    float acc[RB][BQ];
    #pragma unroll
    for (int r = 0; r < RB; ++r)
        #pragma unroll
        for (int b = 0; b < BQ; ++b)
            acc[r][b] = 0.f;

    auto LOAD = [&](Buf& u, int c) {
        const int n0 = c * CC + tc;
        const int g  = n0 >> 4;             // scale group (both cols in same group)
        const int tIdx = ti * TN + g;
        #pragma unroll
        for (int b = 0; b < BQ; ++b)
            u.xv[b] = *reinterpret_cast<const v2f*>(x + b * N_DIM + n0);
        #pragma unroll
        for (int r = 0; r < RB; ++r) {
            const int m = m0 + r;
            u.wc[r]   = *reinterpret_cast<const v2i*>(W + (size_t)m * N_DIM + n0);
            u.sraw[r] = Ws[m * TN + g];
            u.zraw[r] = Wz[m * TN + g];
        }
        u.wss = Wss[tIdx];
        u.wsz = Wsz[tIdx];
        u.wzs = Wzs[tIdx];
        u.wzz = Wzz[tIdx];
    };

    auto COMPUTE = [&](const Buf& u) {
        float w[RB][2];
        #pragma unroll
        for (int r = 0; r < RB; ++r) {
            const float s = ((float)u.sraw[r] - u.wsz) * u.wss;
            const float z = ((float)u.zraw[r] - u.wzz) * u.wzs;
            w[r][0] = ((float)u.wc[r].x - z) * s;
            w[r][1] = ((float)u.wc[r].y - z) * s;
        }
        #pragma unroll
        for (int b = 0; b < BQ; ++b) {
            const v2f xb = u.xv[b];
            #pragma unroll
            for (int r = 0; r < RB; ++r)
                acc[r][b] = fmaf(w[r][1], xb.y, fmaf(w[r][0], xb.x, acc[r][b]));
        }
    };

    Buf A, B;
    LOAD(A, 0);
    // steady state: issue chunk c+1's loads BEFORE computing chunk c
    for (int c = 0; c < NCHUNK - 2; c += 2) {
        LOAD(B, c + 1);
        COMPUTE(A);
        LOAD(A, c + 2);
        COMPUTE(B);
    }
    LOAD(B, NCHUNK - 1);
    COMPUTE(A);
    COMPUTE(B);

    // ---- fused CSR outlier correction: 32 lanes per row, 4 rows = 128 threads ----
    __shared__ float lsp[RB][BQ];
    if (t < RB * 32) {
        const int r = t >> 5;
        const int j = t & 31;
        const int m = m0 + r;
        const int base = row_offsets[m];
        const int cnt  = row_offsets[m + 1] - base;
        float c[BQ];
        #pragma unroll
        for (int b = 0; b < BQ; ++b) c[b] = 0.f;
        for (int jj = j; jj < cnt; jj += 32) {
            const int   col = col_ids[base + jj];
            const float v   = values[base + jj];
            #pragma unroll
            for (int b = 0; b < BQ; ++b)
                c[b] = fmaf(v, x[b * N_DIM + col], c[b]);
        }
        #pragma unroll
        for (int b = 0; b < BQ; ++b) {
            float v = c[b];
            for (int off = 16; off > 0; off >>= 1)
                v += __shfl_xor(v, off, 32);
            c[b] = v;
        }
        if (j == 0) {
            #pragma unroll
            for (int b = 0; b < BQ; ++b)
                lsp[r][b] = c[b];
        }
    }

    // ---- dense reduction: 2-step quad shuffle, then LDS tree ----
    #pragma unroll
    for (int r = 0; r < RB; ++r)
        #pragma unroll
        for (int b = 0; b < BQ; ++b) {
            float v = acc[r][b];
            v += __shfl_xor(v, 1, 64);
            v += __shfl_xor(v, 2, 64);
            acc[r][b] = v;
        }

    __shared__ float lred[64][NOUT + 1];    // 64 quads x 40 outs (+pad)
    if ((t & 3) == 0) {
        const int q = t >> 2;
        #pragma unroll
        for (int r = 0; r < RB; ++r)
            #pragma unroll
            for (int b = 0; b < BQ; ++b)
                lred[q][r * BQ + b] = acc[r][b];
    }
    __shared__ float l2[NOUT][2];
    __syncthreads();

    if (t < 2 * NOUT) {                     // 80 threads: each sums 32 quads
        const int out = t % NOUT;
        const int h   = t / NOUT;
        float v = 0.f;
        #pragma unroll
        for (int q = 0; q < 32; ++q)
            v += lred[h * 32 + q][out];
        l2[out][h] = v;
    }
    __syncthreads();

    if (t < NOUT) {                         // 40 threads: final combine + write
        const int r = t / BQ;
        const int b = t % BQ;
        y[b * M_DIM + (m0 + r)] = l2[t][0] + l2[t][1] + lsp[r][b];
    }
}

extern "C" void kernel_launch(void* const* d_in, const int* in_sizes, int n_in,
                              void* d_out, int out_size, void* d_ws, size_t ws_size,
                              hipStream_t stream)
{
    const float* x    = (const float*)d_in[0];
    const int*   W    = (const int*)  d_in[1];
    const int*   Ws   = (const int*)  d_in[2];
    const int*   Wz   = (const int*)  d_in[3];
    const float* Wss  = (const float*)d_in[4];
    const float* Wsz  = (const float*)d_in[5];
    const float* Wzs  = (const float*)d_in[6];
    const float* Wzz  = (const float*)d_in[7];
    const int*   roff = (const int*)  d_in[8];
    const int*   cids = (const int*)  d_in[9];
    const float* vals = (const float*)d_in[10];
    float* yout = (float*)d_out;

    dim3 grid(M_DIM / RB);                  // 2048 blocks
    dim3 block(NTHREADS);
    spqr_fused<<<grid, block, 0, stream>>>(x, W, Ws, Wz, Wss, Wsz, Wzs, Wzz,
                                           roff, cids, vals, yout);
}